// Round 13
// baseline (99.652 us; speedup 1.0000x reference)
//
#include <hip/hip_runtime.h>
#include <hip/hip_bf16.h>

#define H 768
#define SEQ 256
#define NPAIR 32896                // S*(S+1)/2 = 128*257
#define NTOT 131584                // 4*NPAIR = 1028*128
#define NOUTP 160
#define OFF_H2H 263168u            // 4*32896*2
#define OFF_T2T 9737216u           // OFF_H2H + 4*24*32896*3

#define N_BPK 122880               // 12 chunks * 20 frags * 64 lanes * 8 bf16
#define SCL 2.8853900817779268f    // 2*log2(e): pre-scale L/R so stage tanh needs no mul

#define CH 64                      // k-elems per chunk
#define NCH 12
#define BCH 20480                  // B chunk bytes (unpadded)
#define SLAB_STR 166               // bf16 slab stride (83 words, odd -> conflict-free)

// LDS map: A0 [0,16384) | A1 [16384,32768) | B0 [32768,53248) | B1 [53248,73728) | bc_s [73728,74368)
// epilogue slab [128][166] bf16 = 42496 B aliases [0,42496)
#define LDS_B0 32768
#define LDS_BC 73728

typedef short bf16x8 __attribute__((ext_vector_type(8)));
typedef float f32x4 __attribute__((ext_vector_type(4)));
typedef float f32x16 __attribute__((ext_vector_type(16)));

__device__ __forceinline__ float tanh_s(float xs) {
    // xs = 2*log2(e)*x  ->  tanh(x) = 1 - 2/(exp2(xs)+1)
    float e = __builtin_amdgcn_exp2f(xs);
    return fmaf(-2.0f, __builtin_amdgcn_rcpf(e + 1.0f), 1.0f);
}
__device__ __forceinline__ float bf_lo(int w){ return __uint_as_float(((unsigned)w) << 16); }
__device__ __forceinline__ float bf_hi(int w){ return __uint_as_float(((unsigned)w) & 0xffff0000u); }
__device__ __forceinline__ float bfu(unsigned short u){ return __uint_as_float(((unsigned)u) << 16); }
__device__ __forceinline__ int cvtpk(float lo, float hi) {
    int r;
    asm("v_cvt_pk_bf16_f32 %0, %1, %2" : "=v"(r) : "v"(lo), "v"(hi));
    return r;
}
__device__ __forceinline__ unsigned short bf16r(float x){
    unsigned int u = __float_as_uint(x);
    u += 0x7fffu + ((u >> 16) & 1u);
    return (unsigned short)(u >> 16);
}
__device__ __forceinline__ int4 tanh_pack(int4 lv, int4 rv) {
    int4 st;
    st.x = cvtpk(tanh_s(bf_lo(lv.x) + bf_lo(rv.x)), tanh_s(bf_hi(lv.x) + bf_hi(rv.x)));
    st.y = cvtpk(tanh_s(bf_lo(lv.y) + bf_lo(rv.y)), tanh_s(bf_hi(lv.y) + bf_hi(rv.y)));
    st.z = cvtpk(tanh_s(bf_lo(lv.z) + bf_lo(rv.z)), tanh_s(bf_hi(lv.z) + bf_hi(rv.z)));
    st.w = cvtpk(tanh_s(bf_lo(lv.w) + bf_lo(rv.w)), tanh_s(bf_hi(lv.w) + bf_hi(rv.w)));
    return st;
}

typedef const __attribute__((address_space(1))) unsigned int* as1_u32p;
typedef __attribute__((address_space(3))) unsigned int* as3_u32p;
__device__ __forceinline__ void gload_lds16(const void* g, void* l) {
    __builtin_amdgcn_global_load_lds((as1_u32p)g, (as3_u32p)l, 16, 0, 0);
}

__device__ __forceinline__ int row_start(int i) { return i * SEQ - (i * (i - 1)) / 2; }
__device__ __forceinline__ void pair_ij(int p, int& oi, int& oj) {
    double disc = 263169.0 - 8.0 * (double)p;   // (2S+1)^2 - 8p
    int i = (int)((513.0 - sqrt(disc)) * 0.5);
    if (i > 0 && row_start(i) > p) --i;
    while (row_start(i + 1) <= p) ++i;
    oi = i;
    oj = i + (p - row_start(i));
}
__device__ __forceinline__ int batch_of(int g) {
    return (g >= 3 * NPAIR) ? 3 : (g >= 2 * NPAIR) ? 2 : (g >= NPAIR) ? 1 : 0;
}

// ---------------- kernel 0: pack Bpk (32x32x16 fragment order, unpadded 20480-B chunks) + bc ----------------
// idx = ((c*20 + s*5 + f)*64 + lane)*8 + j  ->  W[n = f*32 + (lane&31)][k = c*64 + s*16 + (lane>>5)*8 + j]
__global__ __launch_bounds__(256) void pack_kernel(
    const float* __restrict__ h2t_w, const float* __restrict__ h2h_w,
    const float* __restrict__ t2t_w, const float* __restrict__ h2t_b,
    const float* __restrict__ h2h_b, const float* __restrict__ t2t_b,
    unsigned short* __restrict__ Bpk, float* __restrict__ bc)
{
    int idx = blockIdx.x * 256 + threadIdx.x;
    if (idx < N_BPK) {
        int j = idx & 7, lane = (idx >> 3) & 63, rest = idx >> 9;
        int fr = rest % 20, c = rest / 20;
        int s = fr / 5, f = fr % 5;
        int n = f * 32 + (lane & 31);
        int k = c * CH + s * 16 + ((lane >> 5) << 3) + j;
        float v = 0.f;
        if (n < 2)        v = h2t_w[n * H + k];
        else if (n < 74)  v = h2h_w[(n - 2) * H + k];
        else if (n < 146) v = t2t_w[(n - 74) * H + k];
        Bpk[idx] = bf16r(v);
    } else if (idx < N_BPK + NOUTP) {
        int q = idx - N_BPK;
        float v = 0.f;
        if (q < 2)        v = h2t_b[q];
        else if (q < 74)  v = h2h_b[q - 2];
        else if (q < 146) v = t2t_b[q - 74];
        bc[q] = v;
    }
}

// ---------------- kernel 1: LB/RB = hidden @ fc_w (bf16 MFMA, reads fc_w f32 directly), pre-scaled ----------------
__global__ __launch_bounds__(256, 2) void lr_mfma(
    const float* __restrict__ hidden, const float* __restrict__ fc_w,
    const float* __restrict__ fc_b,
    unsigned short* __restrict__ LB, unsigned short* __restrict__ RB)
{
    __shared__ __align__(16) char sm[16384];          // A 8KB | B 8KB
    const int tid = threadIdx.x, l = tid & 63, w = tid >> 6;
    const int wm = w >> 1, wn = w & 1;
    const int m0 = blockIdx.x * 64, n0 = blockIdx.y * 64;
    f32x4 acc[2][2] = {};
    for (int c = 0; c < 12; ++c) {
        const int k0 = c * 64;
        #pragma unroll
        for (int it = 0; it < 2; ++it) {              // A: 64 rows x 64 k, cvt f32->bf16
            int idx = tid + it * 256;
            int row = idx >> 3, k8 = idx & 7;
            const float4* src = reinterpret_cast<const float4*>(hidden + (size_t)(m0 + row) * H + k0 + k8 * 8);
            float4 a = src[0], bq = src[1];
            int4 st;
            st.x = cvtpk(a.x, a.y);  st.y = cvtpk(a.z, a.w);
            st.z = cvtpk(bq.x, bq.y); st.w = cvtpk(bq.z, bq.w);
            *reinterpret_cast<int4*>(sm + row * 128 + ((k8 * 16) ^ ((row & 7) << 4))) = st;
        }
        #pragma unroll
        for (int it = 0; it < 2; ++it) {              // B: 64 rows x 64 k from fc_w (f32 -> bf16)
            int idx = tid + it * 256;
            int row = idx >> 3, k8 = idx & 7;
            const float* fsrc = (n0 < H)
                ? fc_w + (size_t)(n0 + row) * (2 * H) + k0 + k8 * 8
                : fc_w + (size_t)(n0 - H + row) * (2 * H) + H + k0 + k8 * 8;
            const float4* src = reinterpret_cast<const float4*>(fsrc);
            float4 a = src[0], bq = src[1];
            int4 st;
            st.x = cvtpk(a.x, a.y);  st.y = cvtpk(a.z, a.w);
            st.z = cvtpk(bq.x, bq.y); st.w = cvtpk(bq.z, bq.w);
            *reinterpret_cast<int4*>(sm + 8192 + row * 128 + ((k8 * 16) ^ ((row & 7) << 4))) = st;
        }
        __syncthreads();
        #pragma unroll
        for (int kk = 0; kk < 2; ++kk) {
            const int sl = kk * 4 + (l >> 4);
            const int swz = (l & 7) << 4;
            bf16x8 af[2], bfr[2];
            #pragma unroll
            for (int a = 0; a < 2; ++a) {
                int row = 32 * wm + 16 * a + (l & 15);
                af[a] = *reinterpret_cast<const bf16x8*>(sm + row * 128 + ((sl * 16) ^ swz));
            }
            #pragma unroll
            for (int f = 0; f < 2; ++f) {
                int row = 32 * wn + 16 * f + (l & 15);
                bfr[f] = *reinterpret_cast<const bf16x8*>(sm + 8192 + row * 128 + ((sl * 16) ^ swz));
            }
            #pragma unroll
            for (int a = 0; a < 2; ++a)
                #pragma unroll
                for (int f = 0; f < 2; ++f)
                    acc[a][f] = __builtin_amdgcn_mfma_f32_16x16x32_bf16(af[a], bfr[f], acc[a][f], 0, 0, 0);
        }
        __syncthreads();
    }
    #pragma unroll
    for (int a = 0; a < 2; ++a)
        #pragma unroll
        for (int f = 0; f < 2; ++f)
            #pragma unroll
            for (int r = 0; r < 4; ++r) {
                int row = m0 + 32 * wm + 16 * a + 4 * (l >> 4) + r;
                int col = n0 + 32 * wn + 16 * f + (l & 15);
                float v = acc[a][f][r];
                if (n0 < H) LB[(size_t)row * H + col] = bf16r((v + fc_b[col]) * SCL);
                else        RB[(size_t)row * H + (col - H)] = bf16r(v * SCL);
            }
}

// ---------------- kernel 2: wave-specialized pair kernel ----------------
// 512 thr: waves 0-3 CONSUMERS (32 rows x 160 cols each, acc 5 x f32x16), waves 4-7 PRODUCERS.
// Per phase c: consumers MFMA chunk c from LDS; producers build chunk c+1 (tanh A-tile + B stage).
// A layout [s][half][row] (16-B units): producer writes AND consumer reads lane-consecutive.
__global__ __launch_bounds__(512, 4) void pair_mfma(
    const unsigned short* __restrict__ LB, const unsigned short* __restrict__ RB,
    const unsigned short* __restrict__ Bpk, const float* __restrict__ bc,
    float* __restrict__ out)
{
    __shared__ __align__(16) char sm[74368];
    float* bc_s = reinterpret_cast<float*>(sm + LDS_BC);

    const int tid = threadIdx.x, l = tid & 63, w = tid >> 6;
    const int g0 = blockIdx.x * 128;                 // NPAIR % 128 == 0 -> no batch straddle
    const int b = batch_of(g0);
    const int p0 = g0 - b * NPAIR;

    if (tid < NOUTP) bc_s[tid] = bc[tid];

    const bool producer = (w >= 4);
    const int half = l >> 5;

    if (producer) {
        const int pw = w - 4;
        const int row = 32 * pw + (l & 31);
        int pi, pj;
        pair_ij(p0 + row, pi, pj);
        const int kb = half << 3;
        const unsigned short* lp = LB + (size_t)(b * SEQ + pi) * H + kb;
        const unsigned short* rp = RB + (size_t)(b * SEQ + pj) * H + kb;
        const char* bsrc = reinterpret_cast<const char*>(Bpk) + pw * 1024 + l * 16;
        const int bdoff = pw * 1024;                 // wave-uniform LDS dest offset within B half
        const int abase = half * 2048 + row * 16;    // + s*4096 + bufsel*16384

        int4 lv0, lv1, lv2, lv3, rv0, rv1, rv2, rv3;

        // prologue: B(0) -> B0 ; LR(0) -> regs ; tanh(0) -> A0 ; issue LR(1)
        #pragma unroll
        for (int r = 0; r < 5; ++r)
            gload_lds16(bsrc + r * 4096, sm + LDS_B0 + bdoff + r * 4096);
        __builtin_amdgcn_sched_barrier(0);
        lv0 = *reinterpret_cast<const int4*>(lp);
        lv1 = *reinterpret_cast<const int4*>(lp + 16);
        lv2 = *reinterpret_cast<const int4*>(lp + 32);
        lv3 = *reinterpret_cast<const int4*>(lp + 48);
        rv0 = *reinterpret_cast<const int4*>(rp);
        rv1 = *reinterpret_cast<const int4*>(rp + 16);
        rv2 = *reinterpret_cast<const int4*>(rp + 32);
        rv3 = *reinterpret_cast<const int4*>(rp + 48);
        {
            char* adst = sm + abase;                 // A0
            *reinterpret_cast<int4*>(adst)         = tanh_pack(lv0, rv0);
            *reinterpret_cast<int4*>(adst + 4096)  = tanh_pack(lv1, rv1);
            *reinterpret_cast<int4*>(adst + 8192)  = tanh_pack(lv2, rv2);
            *reinterpret_cast<int4*>(adst + 12288) = tanh_pack(lv3, rv3);
        }
        lv0 = *reinterpret_cast<const int4*>(lp + CH);
        lv1 = *reinterpret_cast<const int4*>(lp + CH + 16);
        lv2 = *reinterpret_cast<const int4*>(lp + CH + 32);
        lv3 = *reinterpret_cast<const int4*>(lp + CH + 48);
        rv0 = *reinterpret_cast<const int4*>(rp + CH);
        rv1 = *reinterpret_cast<const int4*>(rp + CH + 16);
        rv2 = *reinterpret_cast<const int4*>(rp + CH + 32);
        rv3 = *reinterpret_cast<const int4*>(rp + CH + 48);
        asm volatile("s_waitcnt vmcnt(8) lgkmcnt(0)" ::: "memory");  // drain B(0)+A-writes; keep 8 LR
        __builtin_amdgcn_s_barrier();
        __builtin_amdgcn_sched_barrier(0);

        for (int c = 0; c < NCH - 1; ++c) {          // phase c: build chunk c+1
            const char* bn = bsrc + (size_t)(c + 1) * BCH;
            char* bbufn = sm + LDS_B0 + (((c + 1) & 1) ? BCH : 0) + bdoff;
            #pragma unroll
            for (int r = 0; r < 5; ++r)
                gload_lds16(bn + r * 4096, bbufn + r * 4096);
            __builtin_amdgcn_sched_barrier(0);
            char* adst = sm + (((c + 1) & 1) ? 16384 : 0) + abase;
            *reinterpret_cast<int4*>(adst)         = tanh_pack(lv0, rv0);
            *reinterpret_cast<int4*>(adst + 4096)  = tanh_pack(lv1, rv1);
            *reinterpret_cast<int4*>(adst + 8192)  = tanh_pack(lv2, rv2);
            *reinterpret_cast<int4*>(adst + 12288) = tanh_pack(lv3, rv3);
            const int co = ((c + 2 < NCH) ? (c + 2) : (NCH - 1)) * CH;   // clamp: keep 8 outstanding
            lv0 = *reinterpret_cast<const int4*>(lp + co);
            lv1 = *reinterpret_cast<const int4*>(lp + co + 16);
            lv2 = *reinterpret_cast<const int4*>(lp + co + 32);
            lv3 = *reinterpret_cast<const int4*>(lp + co + 48);
            rv0 = *reinterpret_cast<const int4*>(rp + co);
            rv1 = *reinterpret_cast<const int4*>(rp + co + 16);
            rv2 = *reinterpret_cast<const int4*>(rp + co + 32);
            rv3 = *reinterpret_cast<const int4*>(rp + co + 48);
            asm volatile("s_waitcnt vmcnt(8) lgkmcnt(0)" ::: "memory"); // drain B(c+1)+A-writes
            __builtin_amdgcn_s_barrier();
            __builtin_amdgcn_sched_barrier(0);
        }
        __builtin_amdgcn_s_barrier();                // peeled phase 11 (consumers eat chunk 11)
    } else {
        // CONSUMER: wave w owns rows 32w..32w+31
        const int arow16 = (32 * w + (l & 31)) * 16; // + half*2048 + s*4096
        f32x16 acc[5] = {};
        __builtin_amdgcn_s_barrier();                // matches producer prologue barrier
        for (int c = 0; c < NCH; ++c) {
            const char* abuf = sm + ((c & 1) ? 16384 : 0);
            const char* bbuf = sm + LDS_B0 + ((c & 1) ? BCH : 0);
            #pragma unroll
            for (int s = 0; s < 4; ++s) {
                bf16x8 af = *reinterpret_cast<const bf16x8*>(abuf + s * 4096 + half * 2048 + arow16);
                #pragma unroll
                for (int f = 0; f < 5; ++f) {
                    bf16x8 bfr = *reinterpret_cast<const bf16x8*>(bbuf + ((s * 5 + f) * 64 + l) * 16);
                    acc[f] = __builtin_amdgcn_mfma_f32_32x32x16_bf16(af, bfr, acc[f], 0, 0, 0);
                }
            }
            asm volatile("s_waitcnt lgkmcnt(0)" ::: "memory");   // reads retired before next overwrite
            __builtin_amdgcn_sched_barrier(0);
            __builtin_amdgcn_s_barrier();
        }
        // dump scores: C layout col = lane&31, row = (g&3) + 8*(g>>2) + 4*half
        unsigned short* slab = reinterpret_cast<unsigned short*>(sm);
        #pragma unroll
        for (int f = 0; f < 5; ++f)
            #pragma unroll
            for (int g = 0; g < 16; ++g) {
                int rw = 32 * w + (g & 3) + 8 * (g >> 2) + 4 * half;
                slab[rw * SLAB_STR + f * 32 + (l & 31)] = bf16r(acc[f][g]);
            }
    }
    __syncthreads();                                 // slab complete, visible to all 8 waves

    unsigned short* slab = reinterpret_cast<unsigned short*>(sm);
    if (tid < 256) {                                 // h2t: 128 rows x 2 (flat out idx = 2g+tt)
        int pr = tid >> 1, tt = tid & 1;
        float val = bfu(slab[pr * SLAB_STR + tt]) + bc_s[tt];
        __builtin_nontemporal_store(val, &out[(size_t)(g0 + pr) * 2 + tt]);
    }
    #pragma unroll
    for (int it = 0; it < 12; ++it) {                // 48 rr x 128 rows, rr-major (coalesced stores)
        int item = it * 512 + tid;
        int pr = item & 127, rr = item >> 7;
        int p = p0 + pr;
        int ob = 2 + rr * 3;
        const unsigned short* sp = slab + pr * SLAB_STR + ob;
        float l0 = bfu(sp[0]) + bc_s[ob + 0];
        float l1 = bfu(sp[1]) + bc_s[ob + 1];
        float l2 = bfu(sp[2]) + bc_s[ob + 2];
        float mx = fmaxf(l0, fmaxf(l1, l2));
        float e0 = __expf(l0 - mx), e1 = __expf(l1 - mx), e2 = __expf(l2 - mx);
        float inv = __fdividef(1.0f, e0 + e1 + e2);
        size_t base = (rr < 24)
            ? (size_t)OFF_H2H + ((size_t)(b * 24 + rr) * NPAIR + p) * 3
            : (size_t)OFF_T2T + ((size_t)(b * 24 + rr - 24) * NPAIR + p) * 3;
        __builtin_nontemporal_store(e0 * inv, &out[base + 0]);
        __builtin_nontemporal_store(e1 * inv, &out[base + 1]);
        __builtin_nontemporal_store(e2 * inv, &out[base + 2]);
    }
}

extern "C" void kernel_launch(void* const* d_in, const int* in_sizes, int n_in,
                              void* d_out, int out_size, void* d_ws, size_t ws_size,
                              hipStream_t stream) {
    const float* hidden = (const float*)d_in[0];
    const float* fc_w   = (const float*)d_in[1];
    const float* fc_b   = (const float*)d_in[2];
    const float* h2t_w  = (const float*)d_in[3];
    const float* h2t_b  = (const float*)d_in[4];
    const float* h2h_w  = (const float*)d_in[5];
    const float* h2h_b  = (const float*)d_in[6];
    const float* t2t_w  = (const float*)d_in[7];
    const float* t2t_b  = (const float*)d_in[8];

    char* wsb = (char*)d_ws;
    unsigned short* LBw  = (unsigned short*)(wsb);              // 1024*768 bf16 = 1.5 MB
    unsigned short* RBw  = (unsigned short*)(wsb + 1572864);    // 1.5 MB
    unsigned short* Bpk  = (unsigned short*)(wsb + 3145728);    // 240 KB (unpadded)
    float*          bc   = (float*)        (wsb + 3391488);     // 640 B

    float* out = (float*)d_out;

    pack_kernel<<<(N_BPK + NOUTP + 255) / 256, 256, 0, stream>>>(
        h2t_w, h2h_w, t2t_w, h2t_b, h2h_b, t2t_b, Bpk, bc);
    lr_mfma<<<dim3(16, 24), 256, 0, stream>>>(hidden, fc_w, fc_b, LBw, RBw);
    pair_mfma<<<NTOT / 128, 512, 0, stream>>>(LBw, RBw, Bpk, bc, out);
}

// Round 14
// 89.303 us; speedup vs baseline: 1.1159x; 1.1159x over previous
//
#include <hip/hip_runtime.h>
#include <hip/hip_bf16.h>

#define H 768
#define SEQ 256
#define NPAIR 32896                // S*(S+1)/2 = 64*514
#define NTOT 131584                // 4*NPAIR = 2056*64
#define NOUTP 160
#define OFF_H2H 263168u            // 4*32896*2
#define OFF_T2T 9737216u           // OFF_H2H + 4*24*32896*3

#define N_BPK 122880               // 24 chunks * 10 frags * 64 lanes * 8 bf16 (real slots)
#define SCL 2.8853900817779268f    // 2*log2(e): LB/RB store exp2(SCL*x) = e^{2x}

#define CH 32                      // k-elems per chunk
#define NCH 24
#define BSLOT 12288                // padded B chunk bytes (real 10240)
#define SLAB_STR 166               // bf16 slab stride (83 words, odd -> conflict-free)

typedef short bf16x8 __attribute__((ext_vector_type(8)));
typedef float f32x4 __attribute__((ext_vector_type(4)));

__device__ __forceinline__ float bf_lo(int w){ return __uint_as_float(((unsigned)w) << 16); }
__device__ __forceinline__ float bf_hi(int w){ return __uint_as_float(((unsigned)w) & 0xffff0000u); }
__device__ __forceinline__ float bfu(unsigned short u){ return __uint_as_float(((unsigned)u) << 16); }
__device__ __forceinline__ int cvtpk(float lo, float hi) {
    int r;
    asm("v_cvt_pk_bf16_f32 %0, %1, %2" : "=v"(r) : "v"(lo), "v"(hi));
    return r;
}
__device__ __forceinline__ unsigned short bf16r(float x){
    unsigned int u = __float_as_uint(x);
    u += 0x7fffu + ((u >> 16) & 1u);
    return (unsigned short)(u >> 16);
}
// tanh from precomputed exponentials: e^{2(l+r)} = EL*ER; tanh = 1 - 2/(e+1). 1 trans only.
__device__ __forceinline__ float tanh_e(float el, float er) {
    float e = el * er;
    return fmaf(-2.0f, __builtin_amdgcn_rcpf(e + 1.0f), 1.0f);
}
__device__ __forceinline__ bf16x8 prod_frag(int4 lv, int4 rv) {
    int4 st;
    st.x = cvtpk(tanh_e(bf_lo(lv.x), bf_lo(rv.x)), tanh_e(bf_hi(lv.x), bf_hi(rv.x)));
    st.y = cvtpk(tanh_e(bf_lo(lv.y), bf_lo(rv.y)), tanh_e(bf_hi(lv.y), bf_hi(rv.y)));
    st.z = cvtpk(tanh_e(bf_lo(lv.z), bf_lo(rv.z)), tanh_e(bf_hi(lv.z), bf_hi(rv.z)));
    st.w = cvtpk(tanh_e(bf_lo(lv.w), bf_lo(rv.w)), tanh_e(bf_hi(lv.w), bf_hi(rv.w)));
    return __builtin_bit_cast(bf16x8, st);
}

typedef const __attribute__((address_space(1))) unsigned int* as1_u32p;
typedef __attribute__((address_space(3))) unsigned int* as3_u32p;
__device__ __forceinline__ void gload_lds16(const void* g, void* l) {
    __builtin_amdgcn_global_load_lds((as1_u32p)g, (as3_u32p)l, 16, 0, 0);
}

__device__ __forceinline__ int row_start(int i) { return i * SEQ - (i * (i - 1)) / 2; }
__device__ __forceinline__ void pair_ij(int p, int& oi, int& oj) {
    double disc = 263169.0 - 8.0 * (double)p;   // (2S+1)^2 - 8p
    int i = (int)((513.0 - sqrt(disc)) * 0.5);
    if (i > 0 && row_start(i) > p) --i;
    while (row_start(i + 1) <= p) ++i;
    oi = i;
    oj = i + (p - row_start(i));
}
__device__ __forceinline__ int batch_of(int g) {
    return (g >= 3 * NPAIR) ? 3 : (g >= 2 * NPAIR) ? 2 : (g >= NPAIR) ? 1 : 0;
}

// ---------------- kernel 0: pack Bpk (fragment-ordered, 12KB-strided chunks) + bc ----------------
__global__ __launch_bounds__(256) void pack_kernel(
    const float* __restrict__ h2t_w, const float* __restrict__ h2h_w,
    const float* __restrict__ t2t_w, const float* __restrict__ h2t_b,
    const float* __restrict__ h2h_b, const float* __restrict__ t2t_b,
    unsigned short* __restrict__ Bpk, float* __restrict__ bc)
{
    int idx = blockIdx.x * 256 + threadIdx.x;
    if (idx < N_BPK) {
        int j = idx & 7, lane = (idx >> 3) & 63, rest = idx >> 9;
        int f = rest % 10, c = rest / 10;
        int n = f * 16 + (lane & 15);
        int k = c * CH + ((lane >> 4) << 3) + j;
        float v = 0.f;
        if (n < 2)        v = h2t_w[n * H + k];
        else if (n < 74)  v = h2h_w[(n - 2) * H + k];
        else if (n < 146) v = t2t_w[(n - 74) * H + k];
        Bpk[c * 6144 + (idx - c * 5120)] = bf16r(v);     // 6144 shorts = 12288 B stride
    } else if (idx < N_BPK + NOUTP) {
        int q = idx - N_BPK;
        float v = 0.f;
        if (q < 2)        v = h2t_b[q];
        else if (q < 74)  v = h2h_b[q - 2];
        else if (q < 146) v = t2t_b[q - 74];
        bc[q] = v;
    }
}

// ---------------- kernel 1: LB/RB = exp2(SCL * (hidden @ fc_w [+b])) (bf16 MFMA) ----------------
__global__ __launch_bounds__(256, 2) void lr_mfma(
    const float* __restrict__ hidden, const float* __restrict__ fc_w,
    const float* __restrict__ fc_b,
    unsigned short* __restrict__ LB, unsigned short* __restrict__ RB)
{
    __shared__ __align__(16) char sm[16384];          // A 8KB | B 8KB
    const int tid = threadIdx.x, l = tid & 63, w = tid >> 6;
    const int wm = w >> 1, wn = w & 1;
    const int m0 = blockIdx.x * 64, n0 = blockIdx.y * 64;
    f32x4 acc[2][2] = {};
    for (int c = 0; c < 12; ++c) {
        const int k0 = c * 64;
        #pragma unroll
        for (int it = 0; it < 2; ++it) {              // A: 64 rows x 64 k, cvt f32->bf16
            int idx = tid + it * 256;
            int row = idx >> 3, k8 = idx & 7;
            const float4* src = reinterpret_cast<const float4*>(hidden + (size_t)(m0 + row) * H + k0 + k8 * 8);
            float4 a = src[0], bq = src[1];
            int4 st;
            st.x = cvtpk(a.x, a.y);  st.y = cvtpk(a.z, a.w);
            st.z = cvtpk(bq.x, bq.y); st.w = cvtpk(bq.z, bq.w);
            *reinterpret_cast<int4*>(sm + row * 128 + ((k8 * 16) ^ ((row & 7) << 4))) = st;
        }
        #pragma unroll
        for (int it = 0; it < 2; ++it) {              // B: 64 rows x 64 k from fc_w (f32 -> bf16)
            int idx = tid + it * 256;
            int row = idx >> 3, k8 = idx & 7;
            const float* fsrc = (n0 < H)
                ? fc_w + (size_t)(n0 + row) * (2 * H) + k0 + k8 * 8
                : fc_w + (size_t)(n0 - H + row) * (2 * H) + H + k0 + k8 * 8;
            const float4* src = reinterpret_cast<const float4*>(fsrc);
            float4 a = src[0], bq = src[1];
            int4 st;
            st.x = cvtpk(a.x, a.y);  st.y = cvtpk(a.z, a.w);
            st.z = cvtpk(bq.x, bq.y); st.w = cvtpk(bq.z, bq.w);
            *reinterpret_cast<int4*>(sm + 8192 + row * 128 + ((k8 * 16) ^ ((row & 7) << 4))) = st;
        }
        __syncthreads();
        #pragma unroll
        for (int kk = 0; kk < 2; ++kk) {
            const int sl = kk * 4 + (l >> 4);
            const int swz = (l & 7) << 4;
            bf16x8 af[2], bfr[2];
            #pragma unroll
            for (int a = 0; a < 2; ++a) {
                int row = 32 * wm + 16 * a + (l & 15);
                af[a] = *reinterpret_cast<const bf16x8*>(sm + row * 128 + ((sl * 16) ^ swz));
            }
            #pragma unroll
            for (int f = 0; f < 2; ++f) {
                int row = 32 * wn + 16 * f + (l & 15);
                bfr[f] = *reinterpret_cast<const bf16x8*>(sm + 8192 + row * 128 + ((sl * 16) ^ swz));
            }
            #pragma unroll
            for (int a = 0; a < 2; ++a)
                #pragma unroll
                for (int f = 0; f < 2; ++f)
                    acc[a][f] = __builtin_amdgcn_mfma_f32_16x16x32_bf16(af[a], bfr[f], acc[a][f], 0, 0, 0);
        }
        __syncthreads();
    }
    #pragma unroll
    for (int a = 0; a < 2; ++a)
        #pragma unroll
        for (int f = 0; f < 2; ++f)
            #pragma unroll
            for (int r = 0; r < 4; ++r) {
                int row = m0 + 32 * wm + 16 * a + 4 * (l >> 4) + r;
                int col = n0 + 32 * wn + 16 * f + (l & 15);
                float v = acc[a][f][r];
                if (n0 < H) LB[(size_t)row * H + col] =
                    bf16r(__builtin_amdgcn_exp2f((v + fc_b[col]) * SCL));   // EL = e^{2(L+b)}
                else        RB[(size_t)row * H + (col - H)] =
                    bf16r(__builtin_amdgcn_exp2f(v * SCL));                 // ER = e^{2R}
            }
}

// ---------------- kernel 2: lean-wave pair kernel, 2-chunk-deep LR prefetch (r10 structure) ----------------
// block = 256 thr (4 waves), wave = 16 rows x 160 cols (acc[10]), M = 64 pairs, chunk = 32 k.
// Queue per chunk: B(c+1) x3 -> prod(c) -> LR(c+2) x2 -> MFMA x10 -> vmcnt(2)+barrier.
__global__ __launch_bounds__(256, 4) void pair_mfma(
    const unsigned short* __restrict__ LB, const unsigned short* __restrict__ RB,
    const unsigned short* __restrict__ Bpk, const float* __restrict__ bc,
    float* __restrict__ out)
{
    __shared__ __align__(16) char sm[25216];
    // pre-stage: iOf [0,256) | jOf [256,512)   (aliased into dbuf region)
    // K-loop:   B buf0 [0,12288) | buf1 [12288,24576)
    // epilogue: bf16 slab [64][166] = 21248 B at [0,21248)
    // bc_s [24576,25216) lives throughout
    int*   iOf  = reinterpret_cast<int*>(sm);
    int*   jOf  = reinterpret_cast<int*>(sm + 256);
    float* bc_s = reinterpret_cast<float*>(sm + 24576);

    const int tid = threadIdx.x, l = tid & 63, w = tid >> 6;
    const int g0 = blockIdx.x * 64;                  // block never spans a batch (NPAIR % 64 == 0)
    const int b = batch_of(g0);
    const int p0 = g0 - b * NPAIR;

    if (tid < 64) {
        int i, j; pair_ij(p0 + tid, i, j);
        iOf[tid] = (b * SEQ + i) * H;
        jOf[tid] = (b * SEQ + j) * H;
    }
    if (tid < NOUTP) bc_s[tid] = bc[tid];
    __syncthreads();

    const int row = 16 * w + (l & 15);
    const unsigned short* lp = LB + iOf[row] + ((l >> 4) << 3);
    const unsigned short* rp = RB + jOf[row] + ((l >> 4) << 3);
    __syncthreads();   // iOf/jOf consumed before B staging overwrites [0,512)

    // B: per-thread 3 uniform slots; per-lane src, wave-uniform LDS dest
    const char* bp = reinterpret_cast<const char*>(Bpk) + w * 1024 + l * 16;
    const int d0 = w * 1024;

    f32x4 acc[10] = {};
    int4 lv[3], rv[3];

    {   // prologue: B(0) -> buf0 ; LR(0), LR(1) -> regs (2-deep from the start)
        gload_lds16(bp,        sm + d0);
        gload_lds16(bp + 4096, sm + 4096 + d0);
        gload_lds16(bp + 8192, sm + 8192 + d0);
        __builtin_amdgcn_sched_barrier(0);
    }
    lv[0] = *reinterpret_cast<const int4*>(lp);
    rv[0] = *reinterpret_cast<const int4*>(rp);
    lv[1] = *reinterpret_cast<const int4*>(lp + CH);
    rv[1] = *reinterpret_cast<const int4*>(rp + CH);
    asm volatile("s_waitcnt vmcnt(4)" ::: "memory");   // drain B(0); keep LR0+LR1 in flight
    __builtin_amdgcn_s_barrier();
    __builtin_amdgcn_sched_barrier(0);

    #pragma unroll
    for (int c = 0; c < NCH - 2; ++c) {               // c = 0..21, fully unrolled (static lv idx)
        char* bufn = sm + (((c + 1) & 1) ? BSLOT : 0);
        const char* bn = bp + (c + 1) * BSLOT;
        // phase 1: B(c+1) -> bufn (oldest outstanding after prior drain)
        gload_lds16(bn,        bufn + d0);
        gload_lds16(bn + 4096, bufn + 4096 + d0);
        gload_lds16(bn + 8192, bufn + 8192 + d0);
        __builtin_amdgcn_sched_barrier(0);
        // phase 2: tanh-from-exponentials, chunk c (LR(c) drained by prior vmcnt(2) -> no wait)
        bf16x8 a0 = prod_frag(lv[c % 3], rv[c % 3]);
        // phase 3: issue LR(c+2) into the freed slot (newest: survives this chunk's barrier)
        const int co = (c + 2) * CH;
        lv[(c + 2) % 3] = *reinterpret_cast<const int4*>(lp + co);
        rv[(c + 2) % 3] = *reinterpret_cast<const int4*>(rp + co);
        // phase 4: 10 x {ds_read_b128 + MFMA} on bufc
        const char* bufc = sm + ((c & 1) ? BSLOT : 0);
        #pragma unroll
        for (int f = 0; f < 10; ++f) {
            bf16x8 bfr = *reinterpret_cast<const bf16x8*>(bufc + (f * 64 + l) * 16);
            acc[f] = __builtin_amdgcn_mfma_f32_16x16x32_bf16(a0, bfr, acc[f], 0, 0, 0);
        }
        // phase 5: counted barrier — drains B(c+1) and LR(c+1); leaves LR(c+2) in flight
        asm volatile("s_waitcnt vmcnt(2)" ::: "memory");
        __builtin_amdgcn_s_barrier();
        __builtin_amdgcn_sched_barrier(0);
    }
    {   // peeled chunk 22: stage B(23); no LR issue -> must drain fully (B is newest)
        char* bufn = sm + BSLOT;                      // 23 odd
        const char* bn = bp + 23 * BSLOT;
        gload_lds16(bn,        bufn + d0);
        gload_lds16(bn + 4096, bufn + 4096 + d0);
        gload_lds16(bn + 8192, bufn + 8192 + d0);
        __builtin_amdgcn_sched_barrier(0);
        bf16x8 a0 = prod_frag(lv[22 % 3], rv[22 % 3]);
        const char* bufc = sm;                        // 22 even
        #pragma unroll
        for (int f = 0; f < 10; ++f) {
            bf16x8 bfr = *reinterpret_cast<const bf16x8*>(bufc + (f * 64 + l) * 16);
            acc[f] = __builtin_amdgcn_mfma_f32_16x16x32_bf16(a0, bfr, acc[f], 0, 0, 0);
        }
        asm volatile("s_waitcnt vmcnt(0)" ::: "memory");
        __builtin_amdgcn_s_barrier();
        __builtin_amdgcn_sched_barrier(0);
    }
    {   // peeled chunk 23 (no stage)
        bf16x8 a0 = prod_frag(lv[23 % 3], rv[23 % 3]);
        const char* bufc = sm + BSLOT;                // 23 odd
        #pragma unroll
        for (int f = 0; f < 10; ++f) {
            bf16x8 bfr = *reinterpret_cast<const bf16x8*>(bufc + (f * 64 + l) * 16);
            acc[f] = __builtin_amdgcn_mfma_f32_16x16x32_bf16(a0, bfr, acc[f], 0, 0, 0);
        }
    }
    asm volatile("s_waitcnt lgkmcnt(0)" ::: "memory");   // all LDS reads retired before slab aliases
    __builtin_amdgcn_s_barrier();

    // epilogue: all 4 waves dump 64 rows -> slab, one barrier, parallel softmax
    unsigned short* slab = reinterpret_cast<unsigned short*>(sm);
    #pragma unroll
    for (int f = 0; f < 10; ++f)
        #pragma unroll
        for (int r = 0; r < 4; ++r) {
            int rw = 16 * w + 4 * (l >> 4) + r;
            slab[rw * SLAB_STR + f * 16 + (l & 15)] = bf16r(acc[f][r]);
        }
    __syncthreads();

    if (tid < 128) {                                 // h2t: 64 rows x 2 (flat out idx = 2g+tt)
        int pr = tid >> 1, tt = tid & 1;
        float val = bfu(slab[pr * SLAB_STR + tt]) + bc_s[tt];
        __builtin_nontemporal_store(val, &out[(size_t)(g0 + pr) * 2 + tt]);
    }
    #pragma unroll
    for (int it = 0; it < 12; ++it) {                // 48 rr x 64 rows, rr-major (coalesced stores)
        int item = it * 256 + tid;
        int pr = item & 63, rr = item >> 6;
        int p = p0 + pr;
        int ob = 2 + rr * 3;
        const unsigned short* sp = slab + pr * SLAB_STR + ob;
        float l0 = bfu(sp[0]) + bc_s[ob + 0];
        float l1 = bfu(sp[1]) + bc_s[ob + 1];
        float l2 = bfu(sp[2]) + bc_s[ob + 2];
        float mx = fmaxf(l0, fmaxf(l1, l2));
        float e0 = __expf(l0 - mx), e1 = __expf(l1 - mx), e2 = __expf(l2 - mx);
        float inv = __fdividef(1.0f, e0 + e1 + e2);
        size_t base = (rr < 24)
            ? (size_t)OFF_H2H + ((size_t)(b * 24 + rr) * NPAIR + p) * 3
            : (size_t)OFF_T2T + ((size_t)(b * 24 + rr - 24) * NPAIR + p) * 3;
        __builtin_nontemporal_store(e0 * inv, &out[base + 0]);
        __builtin_nontemporal_store(e1 * inv, &out[base + 1]);
        __builtin_nontemporal_store(e2 * inv, &out[base + 2]);
    }
}

extern "C" void kernel_launch(void* const* d_in, const int* in_sizes, int n_in,
                              void* d_out, int out_size, void* d_ws, size_t ws_size,
                              hipStream_t stream) {
    const float* hidden = (const float*)d_in[0];
    const float* fc_w   = (const float*)d_in[1];
    const float* fc_b   = (const float*)d_in[2];
    const float* h2t_w  = (const float*)d_in[3];
    const float* h2t_b  = (const float*)d_in[4];
    const float* h2h_w  = (const float*)d_in[5];
    const float* h2h_b  = (const float*)d_in[6];
    const float* t2t_w  = (const float*)d_in[7];
    const float* t2t_b  = (const float*)d_in[8];

    char* wsb = (char*)d_ws;
    unsigned short* LBw  = (unsigned short*)(wsb);              // 1024*768 bf16 = 1.5 MB (holds EL)
    unsigned short* RBw  = (unsigned short*)(wsb + 1572864);    // 1.5 MB (holds ER)
    unsigned short* Bpk  = (unsigned short*)(wsb + 3145728);    // 24*12288 B = 288 KB (padded chunks)
    float*          bc   = (float*)        (wsb + 3440640);     // 640 B

    float* out = (float*)d_out;

    pack_kernel<<<(N_BPK + NOUTP + 255) / 256, 256, 0, stream>>>(
        h2t_w, h2h_w, t2t_w, h2t_b, h2h_b, t2t_b, Bpk, bc);
    lr_mfma<<<dim3(16, 24), 256, 0, stream>>>(hidden, fc_w, fc_b, LBw, RBw);
    pair_mfma<<<NTOT / 64, 256, 0, stream>>>(LBw, RBw, Bpk, bc, out);
}

// Round 15
// 86.165 us; speedup vs baseline: 1.1565x; 1.0364x over previous
//
#include <hip/hip_runtime.h>
#include <hip/hip_bf16.h>

#define H 768
#define SEQ 256
#define NPAIR 32896                // S*(S+1)/2 = 64*514
#define NTOT 131584                // 4*NPAIR = 2056*64
#define NOUTP 160
#define OFF_H2H 263168u            // 4*32896*2
#define OFF_T2T 9737216u           // OFF_H2H + 4*24*32896*3

#define N_BPK 122880               // 24 chunks * 10 frags * 64 lanes * 8 bf16 (real slots)
#define SCL 2.8853900817779268f    // 2*log2(e): LB/RB store exp2(SCL*x) = e^{2x}

#define CH 32                      // k-elems per chunk
#define NCH 24
#define BSLOT 12288                // padded B chunk bytes (real 10240)
#define SLAB_STR 166               // bf16 slab stride (83 words, odd -> conflict-free)

#define PACK_BLOCKS 481            // ceil((N_BPK+NOUTP)/256)
#define LR_BLOCKS 384              // 16 x 24

typedef short bf16x8 __attribute__((ext_vector_type(8)));
typedef float f32x4 __attribute__((ext_vector_type(4)));

__device__ __forceinline__ float bf_lo(int w){ return __uint_as_float(((unsigned)w) << 16); }
__device__ __forceinline__ float bf_hi(int w){ return __uint_as_float(((unsigned)w) & 0xffff0000u); }
__device__ __forceinline__ float bfu(unsigned short u){ return __uint_as_float(((unsigned)u) << 16); }
__device__ __forceinline__ int cvtpk(float lo, float hi) {
    int r;
    asm("v_cvt_pk_bf16_f32 %0, %1, %2" : "=v"(r) : "v"(lo), "v"(hi));
    return r;
}
__device__ __forceinline__ unsigned short bf16r(float x){
    unsigned int u = __float_as_uint(x);
    u += 0x7fffu + ((u >> 16) & 1u);
    return (unsigned short)(u >> 16);
}
// tanh from precomputed exponentials: e^{2(l+r)} = EL*ER; tanh = 1 - 2/(e+1). 1 trans only.
__device__ __forceinline__ float tanh_e(float el, float er) {
    float e = el * er;
    return fmaf(-2.0f, __builtin_amdgcn_rcpf(e + 1.0f), 1.0f);
}
__device__ __forceinline__ bf16x8 prod_frag(int4 lv, int4 rv) {
    int4 st;
    st.x = cvtpk(tanh_e(bf_lo(lv.x), bf_lo(rv.x)), tanh_e(bf_hi(lv.x), bf_hi(rv.x)));
    st.y = cvtpk(tanh_e(bf_lo(lv.y), bf_lo(rv.y)), tanh_e(bf_hi(lv.y), bf_hi(rv.y)));
    st.z = cvtpk(tanh_e(bf_lo(lv.z), bf_lo(rv.z)), tanh_e(bf_hi(lv.z), bf_hi(rv.z)));
    st.w = cvtpk(tanh_e(bf_lo(lv.w), bf_lo(rv.w)), tanh_e(bf_hi(lv.w), bf_hi(rv.w)));
    return __builtin_bit_cast(bf16x8, st);
}

typedef const __attribute__((address_space(1))) unsigned int* as1_u32p;
typedef __attribute__((address_space(3))) unsigned int* as3_u32p;
__device__ __forceinline__ void gload_lds16(const void* g, void* l) {
    __builtin_amdgcn_global_load_lds((as1_u32p)g, (as3_u32p)l, 16, 0, 0);
}

__device__ __forceinline__ int row_start(int i) { return i * SEQ - (i * (i - 1)) / 2; }
__device__ __forceinline__ void pair_ij(int p, int& oi, int& oj) {
    double disc = 263169.0 - 8.0 * (double)p;   // (2S+1)^2 - 8p
    int i = (int)((513.0 - sqrt(disc)) * 0.5);
    if (i > 0 && row_start(i) > p) --i;
    while (row_start(i + 1) <= p) ++i;
    oi = i;
    oj = i + (p - row_start(i));
}
__device__ __forceinline__ int batch_of(int g) {
    return (g >= 3 * NPAIR) ? 3 : (g >= 2 * NPAIR) ? 2 : (g >= NPAIR) ? 1 : 0;
}

// ---------------- kernel 0: FUSED setup — pack blocks [0,481) + lr blocks [481,865) ----------------
__global__ __launch_bounds__(256, 2) void setup_kernel(
    const float* __restrict__ hidden, const float* __restrict__ fc_w,
    const float* __restrict__ fc_b,
    const float* __restrict__ h2t_w, const float* __restrict__ h2h_w,
    const float* __restrict__ t2t_w, const float* __restrict__ h2t_b,
    const float* __restrict__ h2h_b, const float* __restrict__ t2t_b,
    unsigned short* __restrict__ Bpk, float* __restrict__ bc,
    unsigned short* __restrict__ LB, unsigned short* __restrict__ RB)
{
    const int tid = threadIdx.x;
    if (blockIdx.x < PACK_BLOCKS) {
        // ---- pack Bpk (fragment-ordered, 12KB-strided chunks) + bc ----
        int idx = blockIdx.x * 256 + tid;
        if (idx < N_BPK) {
            int j = idx & 7, lane = (idx >> 3) & 63, rest = idx >> 9;
            int f = rest % 10, c = rest / 10;
            int n = f * 16 + (lane & 15);
            int k = c * CH + ((lane >> 4) << 3) + j;
            float v = 0.f;
            if (n < 2)        v = h2t_w[n * H + k];
            else if (n < 74)  v = h2h_w[(n - 2) * H + k];
            else if (n < 146) v = t2t_w[(n - 74) * H + k];
            Bpk[c * 6144 + (idx - c * 5120)] = bf16r(v);
        } else if (idx < N_BPK + NOUTP) {
            int q = idx - N_BPK;
            float v = 0.f;
            if (q < 2)        v = h2t_b[q];
            else if (q < 74)  v = h2h_b[q - 2];
            else if (q < 146) v = t2t_b[q - 74];
            bc[q] = v;
        }
        return;
    }
    // ---- lr: LB/RB = exp2(SCL * (hidden @ fc_w [+b])) ----
    __shared__ __align__(16) char sm[16384];          // A 8KB | B 8KB
    const int q = blockIdx.x - PACK_BLOCKS;
    const int m0 = (q & 15) * 64, n0 = (q >> 4) * 64;
    const int l = tid & 63, w = tid >> 6;
    const int wm = w >> 1, wn = w & 1;
    f32x4 acc[2][2] = {};
    for (int c = 0; c < 12; ++c) {
        const int k0 = c * 64;
        #pragma unroll
        for (int it = 0; it < 2; ++it) {              // A: 64 rows x 64 k, cvt f32->bf16
            int idx = tid + it * 256;
            int row = idx >> 3, k8 = idx & 7;
            const float4* src = reinterpret_cast<const float4*>(hidden + (size_t)(m0 + row) * H + k0 + k8 * 8);
            float4 a = src[0], bq = src[1];
            int4 st;
            st.x = cvtpk(a.x, a.y);  st.y = cvtpk(a.z, a.w);
            st.z = cvtpk(bq.x, bq.y); st.w = cvtpk(bq.z, bq.w);
            *reinterpret_cast<int4*>(sm + row * 128 + ((k8 * 16) ^ ((row & 7) << 4))) = st;
        }
        #pragma unroll
        for (int it = 0; it < 2; ++it) {              // B: 64 rows x 64 k from fc_w (f32 -> bf16)
            int idx = tid + it * 256;
            int row = idx >> 3, k8 = idx & 7;
            const float* fsrc = (n0 < H)
                ? fc_w + (size_t)(n0 + row) * (2 * H) + k0 + k8 * 8
                : fc_w + (size_t)(n0 - H + row) * (2 * H) + H + k0 + k8 * 8;
            const float4* src = reinterpret_cast<const float4*>(fsrc);
            float4 a = src[0], bq = src[1];
            int4 st;
            st.x = cvtpk(a.x, a.y);  st.y = cvtpk(a.z, a.w);
            st.z = cvtpk(bq.x, bq.y); st.w = cvtpk(bq.z, bq.w);
            *reinterpret_cast<int4*>(sm + 8192 + row * 128 + ((k8 * 16) ^ ((row & 7) << 4))) = st;
        }
        __syncthreads();
        #pragma unroll
        for (int kk = 0; kk < 2; ++kk) {
            const int sl = kk * 4 + (l >> 4);
            const int swz = (l & 7) << 4;
            bf16x8 af[2], bfr[2];
            #pragma unroll
            for (int a = 0; a < 2; ++a) {
                int row = 32 * wm + 16 * a + (l & 15);
                af[a] = *reinterpret_cast<const bf16x8*>(sm + row * 128 + ((sl * 16) ^ swz));
            }
            #pragma unroll
            for (int f = 0; f < 2; ++f) {
                int row = 32 * wn + 16 * f + (l & 15);
                bfr[f] = *reinterpret_cast<const bf16x8*>(sm + 8192 + row * 128 + ((sl * 16) ^ swz));
            }
            #pragma unroll
            for (int a = 0; a < 2; ++a)
                #pragma unroll
                for (int f = 0; f < 2; ++f)
                    acc[a][f] = __builtin_amdgcn_mfma_f32_16x16x32_bf16(af[a], bfr[f], acc[a][f], 0, 0, 0);
        }
        __syncthreads();
    }
    #pragma unroll
    for (int a = 0; a < 2; ++a)
        #pragma unroll
        for (int f = 0; f < 2; ++f)
            #pragma unroll
            for (int r = 0; r < 4; ++r) {
                int row = m0 + 32 * wm + 16 * a + 4 * (l >> 4) + r;
                int col = n0 + 32 * wn + 16 * f + (l & 15);
                float v = acc[a][f][r];
                if (n0 < H) LB[(size_t)row * H + col] =
                    bf16r(__builtin_amdgcn_exp2f((v + fc_b[col]) * SCL));   // EL = e^{2(L+b)}
                else        RB[(size_t)row * H + (col - H)] =
                    bf16r(__builtin_amdgcn_exp2f(v * SCL));                 // ER = e^{2R}
            }
}

// ---------------- kernel 1: lean-wave pair kernel, B triple-buffered 2 chunks ahead ----------------
// block = 256 thr (4 waves), wave = 16 rows x 160 cols (acc[10]), M = 64 pairs, chunk = 32 k.
// Queue per chunk: B(c+2) x3 -> prod(c) -> LR(c+2) x2 -> setprio(1) MFMA x10 setprio(0)
//                  -> vmcnt(5)+barrier (keeps B(c+2)+LR(c+2) in flight; drains B(c+1),LR(c+1)).
__global__ __launch_bounds__(256, 4) void pair_mfma(
    const unsigned short* __restrict__ LB, const unsigned short* __restrict__ RB,
    const unsigned short* __restrict__ Bpk, const float* __restrict__ bc,
    float* __restrict__ out)
{
    __shared__ __align__(16) char sm[37504];
    // pre-stage: iOf [0,256) | jOf [256,512)   (aliased into buf0, consumed before staging)
    // K-loop:   B buf0 [0,12288) | buf1 [12288,24576) | buf2 [24576,36864)
    // epilogue: bf16 slab [64][166] = 21248 B at [0,21248)
    // bc_s [36864,37504) lives throughout
    int*   iOf  = reinterpret_cast<int*>(sm);
    int*   jOf  = reinterpret_cast<int*>(sm + 256);
    float* bc_s = reinterpret_cast<float*>(sm + 36864);

    const int tid = threadIdx.x, l = tid & 63, w = tid >> 6;
    const int g0 = blockIdx.x * 64;                  // block never spans a batch (NPAIR % 64 == 0)
    const int b = batch_of(g0);
    const int p0 = g0 - b * NPAIR;

    if (tid < 64) {
        int i, j; pair_ij(p0 + tid, i, j);
        iOf[tid] = (b * SEQ + i) * H;
        jOf[tid] = (b * SEQ + j) * H;
    }
    if (tid < NOUTP) bc_s[tid] = bc[tid];
    __syncthreads();

    const int row = 16 * w + (l & 15);
    const unsigned short* lp = LB + iOf[row] + ((l >> 4) << 3);
    const unsigned short* rp = RB + jOf[row] + ((l >> 4) << 3);
    __syncthreads();   // iOf/jOf consumed before B staging overwrites [0,512)

    // B: per-thread 3 uniform slots; per-lane src, wave-uniform LDS dest
    const char* bp = reinterpret_cast<const char*>(Bpk) + w * 1024 + l * 16;
    const int d0 = w * 1024;

    f32x4 acc[10] = {};
    int4 lv[3], rv[3];

    {   // prologue: B(0) -> buf0 ; LR(0) ; B(1) -> buf1 ; LR(1)   (oldest-first order)
        gload_lds16(bp,        sm + d0);
        gload_lds16(bp + 4096, sm + 4096 + d0);
        gload_lds16(bp + 8192, sm + 8192 + d0);
        __builtin_amdgcn_sched_barrier(0);
        lv[0] = *reinterpret_cast<const int4*>(lp);
        rv[0] = *reinterpret_cast<const int4*>(rp);
        gload_lds16(bp + BSLOT,        sm + BSLOT + d0);
        gload_lds16(bp + BSLOT + 4096, sm + BSLOT + 4096 + d0);
        gload_lds16(bp + BSLOT + 8192, sm + BSLOT + 8192 + d0);
        __builtin_amdgcn_sched_barrier(0);
        lv[1] = *reinterpret_cast<const int4*>(lp + CH);
        rv[1] = *reinterpret_cast<const int4*>(rp + CH);
        asm volatile("s_waitcnt vmcnt(7)" ::: "memory");   // drain B(0); keep LR0+B(1)+LR1
        __builtin_amdgcn_s_barrier();
        __builtin_amdgcn_sched_barrier(0);
    }

    #pragma unroll
    for (int c = 0; c < NCH - 2; ++c) {               // c = 0..21, fully unrolled (static %3 idx)
        char* bufn = sm + ((c + 2) % 3) * BSLOT;
        const char* bn = bp + (c + 2) * BSLOT;
        // phase 1: B(c+2) -> bufn (2 chunks ahead)
        gload_lds16(bn,        bufn + d0);
        gload_lds16(bn + 4096, bufn + 4096 + d0);
        gload_lds16(bn + 8192, bufn + 8192 + d0);
        __builtin_amdgcn_sched_barrier(0);
        // phase 2: tanh-from-exponentials, chunk c (LR(c) drained by prior barrier -> no wait)
        bf16x8 a0 = prod_frag(lv[c % 3], rv[c % 3]);
        // phase 3: issue LR(c+2) into the freed slot
        const int co = (c + 2) * CH;
        lv[(c + 2) % 3] = *reinterpret_cast<const int4*>(lp + co);
        rv[(c + 2) % 3] = *reinterpret_cast<const int4*>(rp + co);
        // phase 4: 10 x {ds_read_b128 + MFMA} on buf[c%3], wave priority boosted
        const char* bufc = sm + (c % 3) * BSLOT;
        __builtin_amdgcn_s_setprio(1);
        #pragma unroll
        for (int f = 0; f < 10; ++f) {
            bf16x8 bfr = *reinterpret_cast<const bf16x8*>(bufc + (f * 64 + l) * 16);
            acc[f] = __builtin_amdgcn_mfma_f32_16x16x32_bf16(a0, bfr, acc[f], 0, 0, 0);
        }
        __builtin_amdgcn_s_setprio(0);
        // phase 5: counted barrier — drains B(c+1)+LR(c+1); keeps B(c+2)+LR(c+2) in flight
        asm volatile("s_waitcnt vmcnt(5)" ::: "memory");
        __builtin_amdgcn_s_barrier();
        __builtin_amdgcn_sched_barrier(0);
    }
    {   // peeled chunk 22 (no issues): B(22),LR(22) drained; B(23),LR(23) still in flight
        bf16x8 a0 = prod_frag(lv[22 % 3], rv[22 % 3]);
        const char* bufc = sm + (22 % 3) * BSLOT;
        __builtin_amdgcn_s_setprio(1);
        #pragma unroll
        for (int f = 0; f < 10; ++f) {
            bf16x8 bfr = *reinterpret_cast<const bf16x8*>(bufc + (f * 64 + l) * 16);
            acc[f] = __builtin_amdgcn_mfma_f32_16x16x32_bf16(a0, bfr, acc[f], 0, 0, 0);
        }
        __builtin_amdgcn_s_setprio(0);
        asm volatile("s_waitcnt vmcnt(0)" ::: "memory");   // drain B(23), LR(23)
        __builtin_amdgcn_s_barrier();
        __builtin_amdgcn_sched_barrier(0);
    }
    {   // peeled chunk 23
        bf16x8 a0 = prod_frag(lv[23 % 3], rv[23 % 3]);
        const char* bufc = sm + (23 % 3) * BSLOT;
        #pragma unroll
        for (int f = 0; f < 10; ++f) {
            bf16x8 bfr = *reinterpret_cast<const bf16x8*>(bufc + (f * 64 + l) * 16);
            acc[f] = __builtin_amdgcn_mfma_f32_16x16x32_bf16(a0, bfr, acc[f], 0, 0, 0);
        }
    }
    asm volatile("s_waitcnt lgkmcnt(0)" ::: "memory");   // all LDS reads retired before slab aliases
    __builtin_amdgcn_s_barrier();

    // epilogue: all 4 waves dump 64 rows -> slab, one barrier, parallel softmax
    unsigned short* slab = reinterpret_cast<unsigned short*>(sm);
    #pragma unroll
    for (int f = 0; f < 10; ++f)
        #pragma unroll
        for (int r = 0; r < 4; ++r) {
            int rw = 16 * w + 4 * (l >> 4) + r;
            slab[rw * SLAB_STR + f * 16 + (l & 15)] = bf16r(acc[f][r]);
        }
    __syncthreads();

    if (tid < 128) {                                 // h2t: 64 rows x 2 (flat out idx = 2g+tt)
        int pr = tid >> 1, tt = tid & 1;
        float val = bfu(slab[pr * SLAB_STR + tt]) + bc_s[tt];
        __builtin_nontemporal_store(val, &out[(size_t)(g0 + pr) * 2 + tt]);
    }
    #pragma unroll
    for (int it = 0; it < 12; ++it) {                // 48 rr x 64 rows, rr-major (coalesced stores)
        int item = it * 256 + tid;
        int pr = item & 63, rr = item >> 6;
        int p = p0 + pr;
        int ob = 2 + rr * 3;
        const unsigned short* sp = slab + pr * SLAB_STR + ob;
        float l0 = bfu(sp[0]) + bc_s[ob + 0];
        float l1 = bfu(sp[1]) + bc_s[ob + 1];
        float l2 = bfu(sp[2]) + bc_s[ob + 2];
        float mx = fmaxf(l0, fmaxf(l1, l2));
        float e0 = __expf(l0 - mx), e1 = __expf(l1 - mx), e2 = __expf(l2 - mx);
        float inv = __fdividef(1.0f, e0 + e1 + e2);
        size_t base = (rr < 24)
            ? (size_t)OFF_H2H + ((size_t)(b * 24 + rr) * NPAIR + p) * 3
            : (size_t)OFF_T2T + ((size_t)(b * 24 + rr - 24) * NPAIR + p) * 3;
        __builtin_nontemporal_store(e0 * inv, &out[base + 0]);
        __builtin_nontemporal_store(e1 * inv, &out[base + 1]);
        __builtin_nontemporal_store(e2 * inv, &out[base + 2]);
    }
}

extern "C" void kernel_launch(void* const* d_in, const int* in_sizes, int n_in,
                              void* d_out, int out_size, void* d_ws, size_t ws_size,
                              hipStream_t stream) {
    const float* hidden = (const float*)d_in[0];
    const float* fc_w   = (const float*)d_in[1];
    const float* fc_b   = (const float*)d_in[2];
    const float* h2t_w  = (const float*)d_in[3];
    const float* h2t_b  = (const float*)d_in[4];
    const float* h2h_w  = (const float*)d_in[5];
    const float* h2h_b  = (const float*)d_in[6];
    const float* t2t_w  = (const float*)d_in[7];
    const float* t2t_b  = (const float*)d_in[8];

    char* wsb = (char*)d_ws;
    unsigned short* LBw  = (unsigned short*)(wsb);              // 1024*768 bf16 = 1.5 MB (holds EL)
    unsigned short* RBw  = (unsigned short*)(wsb + 1572864);    // 1.5 MB (holds ER)
    unsigned short* Bpk  = (unsigned short*)(wsb + 3145728);    // 24*12288 B = 288 KB (padded chunks)
    float*          bc   = (float*)        (wsb + 3440640);     // 640 B

    float* out = (float*)d_out;

    setup_kernel<<<PACK_BLOCKS + LR_BLOCKS, 256, 0, stream>>>(
        hidden, fc_w, fc_b, h2t_w, h2h_w, t2t_w, h2t_b, h2h_b, t2t_b,
        Bpk, bc, LBw, RBw);
    pair_mfma<<<NTOT / 64, 256, 0, stream>>>(LBw, RBw, Bpk, bc, out);
}